// Round 3
// baseline (11807.584 us; speedup 1.0000x reference)
//
#include <hip/hip_runtime.h>
#include <math.h>

#define BB 32
#define HH 512
#define VV 32000
#define TT 64
#define GRID 256          // persistent blocks (1 per CU)
#define NLOG 250          // blocks doing logits (128 rows each)
#define RPB 128           // rows per logits block

typedef unsigned long long ull;

// Workspace layout (float offsets)
#define OFF_H0T   0        // 2 x [512][32]
#define OFF_H1T   32768    // 2 x [512][32]
#define OFF_C0    65536    // [hu][b]
#define OFF_C1    81920
#define OFF_PC0   98304    // [2048][32] ctx-part of L0 gates + biases
#define OFF_AMAX2 163840   // 2 x 32 ull (double-buffered argmax keys)
#define OFF_BAR   163968   // 512 u32: flags[256] @0, done fan-out @320
#define OFF_PAIRS 164480   // [TT][NLOG][64] per-tile (m[32], s[32])

typedef float f32x4_ __attribute__((ext_vector_type(4)));

__device__ __forceinline__ float sigmoidf_(float x) { return 1.0f / (1.0f + expf(-x)); }

__device__ __forceinline__ float dot4(const float4 wv, const float4 xv) {
    return wv.x * xv.x + wv.y * xv.y + wv.z * xv.z + wv.w * xv.w;
}
__device__ __forceinline__ void bcast_fma(float* A, const float4 wv,
                                          const float4 x0, const float4 x1,
                                          const float4 x2, const float4 x3) {
    A[0] += wv.x * x0.x + wv.y * x1.x + wv.z * x2.x + wv.w * x3.x;
    A[1] += wv.x * x0.y + wv.y * x1.y + wv.z * x2.y + wv.w * x3.y;
    A[2] += wv.x * x0.z + wv.y * x1.z + wv.z * x2.z + wv.w * x3.z;
    A[3] += wv.x * x0.w + wv.y * x1.w + wv.z * x2.w + wv.w * x3.w;
}

// ---------------------------------------------------------------------------
__global__ void k_init(float* __restrict__ ws) {
    int idx = blockIdx.x * 256 + threadIdx.x;   // 64 x 256 = 16384
    ws[OFF_H0T + idx] = 0.0f;
    ws[OFF_H1T + idx] = 0.0f;
    ws[OFF_C0 + idx]  = 0.0f;
    ws[OFF_C1 + idx]  = 0.0f;
    if (idx < 64) {   // amax2: buf0 = tok 1 keys, buf1 = 0
        ((ull*)(ws + OFF_AMAX2))[idx] = (idx < 32) ? 0xFFFFFFFEull : 0ull;
    }
    if (idx < 512) ((unsigned*)(ws + OFF_BAR))[idx] = 0u;
}

// ---------------------------------------------------------------------------
// pc0[r][b] = sum_k Wih0[r][512+k]*ctx[b][k] + bih0[r] + bhh0[r]   (unchanged)
// ---------------------------------------------------------------------------
__global__ __launch_bounds__(256, 4) void k_pc0(
    const float* __restrict__ Wih0, const float* __restrict__ ctx,
    const float* __restrict__ bih0, const float* __restrict__ bhh0,
    float* __restrict__ pc0)
{
    __shared__ float red[16][16][32];
    const int tid = threadIdx.x;
    const int ks = tid >> 4, bg = (tid >> 2) & 3, rg = tid & 3;
    const int hu = blockIdx.x * 4 + rg;
    const int k0 = ks * 32, b0 = bg * 8;

    float acc[4][8];
#pragma unroll
    for (int g = 0; g < 4; ++g)
#pragma unroll
        for (int j = 0; j < 8; ++j) acc[g][j] = 0.0f;

    const float* wp[4];
#pragma unroll
    for (int g = 0; g < 4; ++g) wp[g] = Wih0 + (size_t)(g * 512 + hu) * 1024 + 512 + k0;

#pragma unroll 2
    for (int kk4 = 0; kk4 < 8; ++kk4) {
        const int kk = kk4 * 4;
        float4 w4[4];
#pragma unroll
        for (int g = 0; g < 4; ++g) w4[g] = *(const float4*)(wp[g] + kk);
#pragma unroll
        for (int j = 0; j < 8; ++j) {
            const float4 xe = *(const float4*)(ctx + (size_t)(b0 + j) * 512 + k0 + kk);
#pragma unroll
            for (int g = 0; g < 4; ++g) acc[g][j] += dot4(w4[g], xe);
        }
    }

#pragma unroll
    for (int g = 0; g < 4; ++g) {
        *(float4*)&red[ks][g * 4 + rg][b0]     = make_float4(acc[g][0], acc[g][1], acc[g][2], acc[g][3]);
        *(float4*)&red[ks][g * 4 + rg][b0 + 4] = make_float4(acc[g][4], acc[g][5], acc[g][6], acc[g][7]);
    }
    __syncthreads();
    if (tid < 128) {
        const int huL = (tid >> 5) & 3, b = tid & 31;
#pragma unroll
        for (int g = 0; g < 4; ++g) {
            float s = 0.0f;
#pragma unroll
            for (int k = 0; k < 16; ++k) s += red[k][g * 4 + huL][b];
            const int row = g * 512 + blockIdx.x * 4 + huL;
            pc0[(size_t)row * 32 + b] = s + bih0[row] + bhh0[row];
        }
    }
}

// ---------------------------------------------------------------------------
// Device-scope grid barrier (monotone targets; flags zeroed by k_init).
// Release: __threadfence + atomicExch(flag). Block 0 wave polls all flags,
// fans out 4 done copies. Acquire: __threadfence after observing done.
// ---------------------------------------------------------------------------
__device__ __forceinline__ void gbar(unsigned* flags, unsigned* done, unsigned target) {
    __syncthreads();
    if (threadIdx.x == 0) {
        __threadfence();
        atomicExch(&flags[blockIdx.x], target);
    }
    if (blockIdx.x == 0 && threadIdx.x < 64) {
#pragma unroll
        for (int i = 0; i < GRID / 64; ++i) {
            unsigned* f = &flags[i * 64 + threadIdx.x];
            while (atomicAdd(f, 0u) < target) __builtin_amdgcn_s_sleep(1);
        }
        if (threadIdx.x < 4) atomicExch(&done[threadIdx.x * 32], target);
    }
    if (threadIdx.x == 0 && blockIdx.x != 0) {
        unsigned* d = &done[(blockIdx.x & 3) * 32];
        while (atomicAdd(d, 0u) < target) __builtin_amdgcn_s_sleep(1);
    }
    if (threadIdx.x == 0) __threadfence();
    __syncthreads();
}

// ---------------------------------------------------------------------------
// LSTM phase (persistent). 2 hu per block, 8 waves: wave = (K-chunk c<<1)|hu_l.
// Per lane (ks8 x bq8): 4 gates x 4 b x 32 k. Butterfly over ks, LDS over c.
// ---------------------------------------------------------------------------
template <int MODE>
__device__ __forceinline__ void lstm_phase(
    const int blk, const int tid,
    const float* __restrict__ Wa, const float* __restrict__ Wb,
    const float* __restrict__ xA, const float* __restrict__ xB,
    const float* __restrict__ emb,
    const ull* __restrict__ amax_rd,
    const float* __restrict__ pc0,
    const float* __restrict__ bih, const float* __restrict__ bhh,
    float* __restrict__ hT_out, float* __restrict__ c_st,
    ull* __restrict__ amax_zero,
    float (*__restrict__ part)[4][32])
{
    constexpr int SA = (MODE == 0) ? 1024 : 512;
    const int w = tid >> 6, lane = tid & 63, ks = lane >> 3, bq = lane & 7;
    const int hu = blk * 2 + (w & 1);
    const int c  = w >> 1;                 // K-chunk (256 k each)
    const int k0 = c * 256 + ks * 32;
    const bool partA = (k0 < 512);
    const int ka = partA ? k0 : k0 - 512;
    const int b0 = bq * 4;

    float acc[4][4];
#pragma unroll
    for (int g = 0; g < 4; ++g)
#pragma unroll
        for (int j = 0; j < 4; ++j) acc[g][j] = 0.0f;

    const float* wp[4];
#pragma unroll
    for (int g = 0; g < 4; ++g)
        wp[g] = partA ? (Wa + (size_t)(g * 512 + hu) * SA + ka)
                      : (Wb + (size_t)(g * 512 + hu) * 512 + ka);

    const float* ep[4];
    if (MODE == 0 && partA) {
#pragma unroll
        for (int j = 0; j < 4; ++j) {
            const int tok = (int)(0xFFFFFFFFu - (unsigned)(amax_rd[b0 + j] & 0xFFFFFFFFull));
            ep[j] = emb + (size_t)tok * 512 + ka;
        }
    }
    const float* xp = (partA ? xA : xB) + (size_t)ka * 32 + b0;

#pragma unroll
    for (int kk4 = 0; kk4 < 8; ++kk4) {
        const int kk = kk4 * 4;
        float4 w4[4];
#pragma unroll
        for (int g = 0; g < 4; ++g) w4[g] = *(const float4*)(wp[g] + kk);
        if (MODE == 0 && partA) {
#pragma unroll
            for (int j = 0; j < 4; ++j) {
                const float4 xe = *(const float4*)(ep[j] + kk);
#pragma unroll
                for (int g = 0; g < 4; ++g) acc[g][j] += dot4(w4[g], xe);
            }
        } else {
            const float4 x0 = *(const float4*)(xp + (size_t)(kk + 0) * 32);
            const float4 x1 = *(const float4*)(xp + (size_t)(kk + 1) * 32);
            const float4 x2 = *(const float4*)(xp + (size_t)(kk + 2) * 32);
            const float4 x3 = *(const float4*)(xp + (size_t)(kk + 3) * 32);
#pragma unroll
            for (int g = 0; g < 4; ++g) bcast_fma(acc[g], w4[g], x0, x1, x2, x3);
        }
    }

    // reduce over ks (lane bits 3..5)
#pragma unroll
    for (int off = 8; off <= 32; off <<= 1)
#pragma unroll
        for (int g = 0; g < 4; ++g)
#pragma unroll
            for (int j = 0; j < 4; ++j)
                acc[g][j] += __shfl_xor(acc[g][j], off, 64);

    if (ks < 4)
        *(float4*)&part[w][ks][b0] = make_float4(acc[ks][0], acc[ks][1], acc[ks][2], acc[ks][3]);

    // zero next-parity amax buffer (read last at t-1's gather, filled by this
    // step's logits after two more barriers)
    if (MODE == 0 && blk == GRID - 1 && tid >= 64 && tid < 96)
        amax_zero[tid - 64] = 0ull;

    __syncthreads();

    if (tid < 64) {
        const int hl = tid >> 5, b = tid & 31;
        const int hu2 = blk * 2 + hl;
        float gate[4];
#pragma unroll
        for (int g = 0; g < 4; ++g) {
            float s = part[hl][g][b] + part[2 + hl][g][b]
                    + part[4 + hl][g][b] + part[6 + hl][g][b];
            const int row = g * 512 + hu2;
            s += (MODE == 0) ? pc0[(size_t)row * 32 + b] : (bih[row] + bhh[row]);
            gate[g] = s;
        }
        const float gi = sigmoidf_(gate[0]);
        const float gf = sigmoidf_(gate[1]);
        const float gn = tanhf(gate[2]);
        const float go = sigmoidf_(gate[3]);
        const int ci = hu2 * 32 + b;
        const float cn = gf * c_st[ci] + gi * gn;
        c_st[ci] = cn;
        hT_out[ci] = go * tanhf(cn);
    }
}

// ---------------------------------------------------------------------------
// Logits phase: 250 blocks x 128 rows. 8 waves x (2 passes x 8 rows).
// Per lane (ks8 x bq8): 8 rows x 4 b x 64 k; butterfly over ks; LDS transpose
// (stride 33) -> coalesced float4 stores; per-b argmax + (m,s) pair.
// ---------------------------------------------------------------------------
__device__ __forceinline__ void logits_phase(
    const int blk, const int tid, const int t,
    const float* __restrict__ h1, const float* __restrict__ Wout,
    const float* __restrict__ bout, float* __restrict__ out,
    ull* __restrict__ amax_wr, float* __restrict__ pairs,
    float (*__restrict__ trans)[33])
{
    if (blk >= NLOG) return;
    const int w = tid >> 6, lane = tid & 63, ks = lane >> 3, bq = lane & 7;
    const int row0 = blk * RPB;
    const int b0 = bq * 4, k0 = ks * 64;
    const float* xb = h1 + (size_t)k0 * 32 + b0;

#pragma unroll
    for (int pass = 0; pass < 2; ++pass) {
        const int rbase = w * 16 + pass * 8;   // local row base of this wave-pass
        const float* wbase = Wout + (size_t)(row0 + rbase) * 512 + k0;
        float acc[8][4];
#pragma unroll
        for (int r = 0; r < 8; ++r)
#pragma unroll
            for (int j = 0; j < 4; ++j) acc[r][j] = 0.0f;

#pragma unroll 4
        for (int kk4 = 0; kk4 < 16; ++kk4) {
            const int kk = kk4 * 4;
            const float4 x0 = *(const float4*)(xb + (size_t)(kk + 0) * 32);
            const float4 x1 = *(const float4*)(xb + (size_t)(kk + 1) * 32);
            const float4 x2 = *(const float4*)(xb + (size_t)(kk + 2) * 32);
            const float4 x3 = *(const float4*)(xb + (size_t)(kk + 3) * 32);
#pragma unroll
            for (int r = 0; r < 8; ++r) {
                const float4 w4 = *(const float4*)(wbase + (size_t)r * 512 + kk);
                bcast_fma(acc[r], w4, x0, x1, x2, x3);
            }
        }
        // reduce over ks (lane bits 3..5)
#pragma unroll
        for (int off = 8; off <= 32; off <<= 1)
#pragma unroll
            for (int r = 0; r < 8; ++r)
#pragma unroll
                for (int j = 0; j < 4; ++j)
                    acc[r][j] += __shfl_xor(acc[r][j], off, 64);

        const float bias = bout[row0 + rbase + ks];
#pragma unroll
        for (int j = 0; j < 4; ++j)
            trans[rbase + ks][b0 + j] = acc[ks][j] + bias;
    }
    __syncthreads();

    // coalesced stores + per-b argmax + per-tile (m, s)
    const int b = tid >> 4, q = tid & 15;
    const size_t obase = ((size_t)b * TT + t) * VV + row0;
    ull best = 0ull;
    float m = -1e30f, ssum = 0.0f;
#pragma unroll
    for (int h = 0; h < 2; ++h) {
        const int r = q * 8 + h * 4;
        float4 v;
        v.x = trans[r + 0][b]; v.y = trans[r + 1][b];
        v.z = trans[r + 2][b]; v.w = trans[r + 3][b];
        *(float4*)(out + obase + r) = v;
        const float vv[4] = { v.x, v.y, v.z, v.w };
#pragma unroll
        for (int i = 0; i < 4; ++i) {
            const float x = vv[i];
            unsigned u = __float_as_uint(x);
            u = (u & 0x80000000u) ? ~u : (u | 0x80000000u);
            const unsigned row = (unsigned)(row0 + r + i);
            const ull key = ((ull)u << 32) | (ull)(0xFFFFFFFFu - row);
            best = best > key ? best : key;
            const float nm = fmaxf(m, x);
            ssum = ssum * __expf(m - nm) + __expf(x - nm);
            m = nm;
        }
    }
#pragma unroll
    for (int off = 1; off < 16; off <<= 1) {
        const ull ob = __shfl_xor(best, off, 64);
        best = best > ob ? best : ob;
        const float om = __shfl_xor(m, off, 64);
        const float os = __shfl_xor(ssum, off, 64);
        const float nm = fmaxf(m, om);
        ssum = ssum * __expf(m - nm) + os * __expf(om - nm);
        m = nm;
    }
    if (q == 0) {
        atomicMax(&amax_wr[b], best);
        if (pairs) {
            float* pr = pairs + ((size_t)t * NLOG + blk) * 64;
            pr[b] = m;
            pr[32 + b] = ssum;
        }
    }
}

// ---------------------------------------------------------------------------
// Persistent decode: 64 steps, 3 grid barriers each, in ONE kernel.
// ---------------------------------------------------------------------------
__global__ __launch_bounds__(512) void k_decode(
    const float* __restrict__ Wih0, const float* __restrict__ Whh0,
    const float* __restrict__ Wih1, const float* __restrict__ Whh1,
    const float* __restrict__ bih1, const float* __restrict__ bhh1,
    const float* __restrict__ emb,  const float* __restrict__ Wout,
    const float* __restrict__ bout, float* __restrict__ out,
    float* __restrict__ ws, int use_pairs)
{
    __shared__ float s_part[8][4][32];
    __shared__ float s_trans[RPB][33];

    const int blk = blockIdx.x, tid = threadIdx.x;
    float* h0a = ws + OFF_H0T;  float* h0b = h0a + 16384;
    float* h1a = ws + OFF_H1T;  float* h1b = h1a + 16384;
    float* c0  = ws + OFF_C0;   float* c1  = ws + OFF_C1;
    const float* pc0 = ws + OFF_PC0;
    ull* amax2 = (ull*)(ws + OFF_AMAX2);
    unsigned* flags = (unsigned*)(ws + OFF_BAR);
    unsigned* done  = flags + 320;
    float* pairs = use_pairs ? (ws + OFF_PAIRS) : nullptr;

    unsigned bar = 0;
    for (int t = 0; t < TT; ++t) {
        const int pp = t & 1;
        float* h0p = pp ? h0b : h0a;  float* h0n = pp ? h0a : h0b;
        float* h1p = pp ? h1b : h1a;  float* h1n = pp ? h1a : h1b;
        ull* amax_rd = amax2 + (size_t)(t & 1) * 32;
        ull* amax_wr = amax2 + (size_t)((t + 1) & 1) * 32;

        lstm_phase<0>(blk, tid, Wih0, Whh0, emb, h0p, emb,
                      amax_rd, pc0, nullptr, nullptr, h0n, c0, amax_wr, s_part);
        gbar(flags, done, ++bar);
        lstm_phase<1>(blk, tid, Wih1, Whh1, h0n, h1p, nullptr,
                      nullptr, nullptr, bih1, bhh1, h1n, c1, nullptr, s_part);
        gbar(flags, done, ++bar);
        logits_phase(blk, tid, t, h1n, Wout, bout, out, amax_wr, pairs, s_trans);
        gbar(flags, done, ++bar);
    }
}

// ---------------------------------------------------------------------------
// log-softmax. With pairs: combine 250 per-tile (m,s) then ONE sweep.
// ---------------------------------------------------------------------------
__global__ __launch_bounds__(256) void k_lsm(float* __restrict__ out,
                                             const float* __restrict__ pairs) {
    float* p = out + (size_t)blockIdx.x * VV;
    const int tid = threadIdx.x;
    __shared__ float sm[4], ss[4];

    float m = -1e30f, s = 0.0f;
    if (pairs) {
        const int b = blockIdx.x >> 6, t = blockIdx.x & 63;
        const float* pr = pairs + (size_t)t * NLOG * 64 + b;
        for (int tile = tid; tile < NLOG; tile += 256) {
            const float tm = pr[(size_t)tile * 64];
            const float ts = pr[(size_t)tile * 64 + 32];
            const float nm = fmaxf(m, tm);
            s = s * __expf(m - nm) + ts * __expf(tm - nm);
            m = nm;
        }
    } else {
        for (int i = tid * 4; i < VV; i += 1024) {
            const float4 v = *(const float4*)(p + i);
            const float cm = fmaxf(fmaxf(v.x, v.y), fmaxf(v.z, v.w));
            const float nm = fmaxf(m, cm);
            s = s * __expf(m - nm) + __expf(v.x - nm) + __expf(v.y - nm)
                                   + __expf(v.z - nm) + __expf(v.w - nm);
            m = nm;
        }
    }
#pragma unroll
    for (int off = 32; off > 0; off >>= 1) {
        const float om = __shfl_down(m, off, 64);
        const float os = __shfl_down(s, off, 64);
        const float nm = fmaxf(m, om);
        s = s * __expf(m - nm) + os * __expf(om - nm);
        m = nm;
    }
    if ((tid & 63) == 0) { sm[tid >> 6] = m; ss[tid >> 6] = s; }
    __syncthreads();
    float M = sm[0], S = ss[0];
#pragma unroll
    for (int w = 1; w < 4; ++w) {
        const float nm = fmaxf(M, sm[w]);
        S = S * __expf(M - nm) + ss[w] * __expf(sm[w] - nm);
        M = nm;
    }
    const float lz = M + __logf(S);
    for (int i = tid * 4; i < VV; i += 1024) {
        f32x4_ v = *(const f32x4_*)(p + i);
        v = v - lz;
        __builtin_nontemporal_store(v, (f32x4_*)(p + i));
    }
}

// ---------------------------------------------------------------------------
extern "C" void kernel_launch(void* const* d_in, const int* in_sizes, int n_in,
                              void* d_out, int out_size, void* d_ws, size_t ws_size,
                              hipStream_t stream) {
    const float* ctx  = (const float*)d_in[0];
    const float* emb  = (const float*)d_in[1];
    const float* Wih0 = (const float*)d_in[2];
    const float* Whh0 = (const float*)d_in[3];
    const float* bih0 = (const float*)d_in[4];
    const float* bhh0 = (const float*)d_in[5];
    const float* Wih1 = (const float*)d_in[6];
    const float* Whh1 = (const float*)d_in[7];
    const float* bih1 = (const float*)d_in[8];
    const float* bhh1 = (const float*)d_in[9];
    const float* Wout = (const float*)d_in[10];
    const float* bout = (const float*)d_in[11];

    float* out = (float*)d_out;
    float* ws  = (float*)d_ws;

    const size_t need_bytes = (size_t)(OFF_PAIRS + (size_t)TT * NLOG * 64) * sizeof(float);
    const int use_pairs = (ws_size >= need_bytes) ? 1 : 0;

    k_init<<<64, 256, 0, stream>>>(ws);
    k_pc0<<<128, 256, 0, stream>>>(Wih0, ctx, bih0, bhh0, ws + OFF_PC0);
    k_decode<<<GRID, 512, 0, stream>>>(Wih0, Whh0, Wih1, Whh1, bih1, bhh1,
                                       emb, Wout, bout, out, ws, use_pairs);
    k_lsm<<<BB * TT, 256, 0, stream>>>(out, use_pairs ? (ws + OFF_PAIRS) : nullptr);
}